// Round 1
// baseline (321.225 us; speedup 1.0000x reference)
//
#include <hip/hip_runtime.h>
#include <math.h>

#define BB    16
#define NN    64
#define EE    512
#define CIMG  512
#define H1D   256
#define H2D   128
#define H3D   64
#define UD    8
#define RD    8
#define BBCD  9
#define EH1D  64
#define EH2D  64
#define EPSF  1e-5f

// ---------------------------------------------------------------------------
// Kernel 1: per-batch prep — build see/count, attr -> P,Q (first edge layer
// split: pair@we1 = attr_i@we1[:9] + attr_j@we1[9:], be1 folded into Q).
// Grid: BB blocks x 256 threads.
// ---------------------------------------------------------------------------
__global__ __launch_bounds__(256) void prep_kernel(
    const int* __restrict__ edge_index,
    const float* __restrict__ bboxes,
    const float* __restrict__ dirs,
    const float* __restrict__ prios,
    const float* __restrict__ we1,
    const float* __restrict__ be1,
    int* __restrict__ see, int* __restrict__ cnt,
    float* __restrict__ P, float* __restrict__ Q)
{
    __shared__ int src_s[EE];
    __shared__ int dst_s[EE];
    __shared__ int see_s[NN * NN];
    __shared__ int deg_s[NN];
    __shared__ float attr_s[NN][BBCD];
    __shared__ float we1_s[2 * BBCD * EH1D];

    const int b = blockIdx.x;
    const int t = threadIdx.x;

    const int* ei = edge_index + b * 2 * EE;
    for (int e = t; e < EE; e += 256) {
        src_s[e] = ei[e];
        dst_s[e] = ei[EE + e];
    }
    for (int x = t; x < NN * NN; x += 256)
        see_s[x] = ((x & (NN - 1)) == 0) ? (x >> 6) : 0;
    if (t < NN) deg_s[t] = 0;
    for (int x = t; x < 2 * BBCD * EH1D; x += 256) we1_s[x] = we1[x];
    if (t < NN) {
        const float* bbp = bboxes + (b * NN + t) * 4;
        const float* ddp = dirs + (b * NN + t) * 4;
        attr_s[t][0] = bbp[0] * (1.0f / 1024.0f);
        attr_s[t][1] = bbp[1] * (1.0f / 1024.0f);
        attr_s[t][2] = bbp[2] * (1.0f / 1024.0f);
        attr_s[t][3] = bbp[3] * (1.0f / 1024.0f);
        attr_s[t][4] = ddp[0];
        attr_s[t][5] = ddp[1];
        attr_s[t][6] = ddp[2];
        attr_s[t][7] = ddp[3];
        attr_s[t][8] = prios[b * NN + t];
    }
    __syncthreads();

    // per-edge rank among earlier same-dst edges; scatter into see
    for (int e = t; e < EE; e += 256) {
        int d = dst_s[e];
        int p = 1;
        for (int j = 0; j < e; ++j) p += (dst_s[j] == d) ? 1 : 0;
        if (p < NN) see_s[d * NN + p] = src_s[e];
        atomicAdd(&deg_s[d], 1);
    }
    __syncthreads();

    for (int x = t; x < NN * NN; x += 256) see[b * NN * NN + x] = see_s[x];
    if (t < NN) {
        int c = deg_s[t] + 1;
        cnt[b * NN + t] = (c < NN) ? c : NN;
    }

    // P[n][o] = attr[n] @ we1[:9, o];  Q[n][o] = attr[n] @ we1[9:, o] + be1[o]
    for (int x = t; x < NN * EH1D; x += 256) {
        int n = x >> 6, o = x & 63;
        float p = 0.f;
        float q = be1[o];
        #pragma unroll
        for (int c = 0; c < BBCD; ++c) {
            float a = attr_s[n][c];
            p += a * we1_s[c * EH1D + o];
            q += a * we1_s[(BBCD + c) * EH1D + o];
        }
        P[(b * NN + n) * EH1D + o] = p;
        Q[(b * NN + n) * EH1D + o] = q;
    }
}

// ---------------------------------------------------------------------------
// Kernel 2: node MLP  x(1024,512) -> node_c(1024,8)
// Grid: 256 blocks x 256 threads, 4 rows per block. BN folded to scale+offset.
// ---------------------------------------------------------------------------
__global__ __launch_bounds__(256) void node_mlp_kernel(
    const float* __restrict__ roi,
    const float* __restrict__ w1, const float* __restrict__ b1,
    const float* __restrict__ g1, const float* __restrict__ bt1,
    const float* __restrict__ m1, const float* __restrict__ v1,
    const float* __restrict__ w2, const float* __restrict__ b2,
    const float* __restrict__ g2, const float* __restrict__ bt2,
    const float* __restrict__ m2, const float* __restrict__ v2,
    const float* __restrict__ w3, const float* __restrict__ b3,
    const float* __restrict__ wn, const float* __restrict__ bnc,
    float* __restrict__ node_c)
{
    __shared__ float x_s[4][CIMG];
    __shared__ float h1_s[4][H1D];
    __shared__ float h2_s[4][H2D];
    __shared__ float h3_s[4][H3D];

    const int t = threadIdx.x;
    const int row0 = blockIdx.x * 4;

    const float4* src = (const float4*)(roi + (size_t)row0 * CIMG);
    float4* dstv = (float4*)&x_s[0][0];
    for (int x = t; x < 4 * CIMG / 4; x += 256) dstv[x] = src[x];
    __syncthreads();

    // layer 1: o = t (256 outs), 4 rows
    {
        float a0 = 0.f, a1 = 0.f, a2 = 0.f, a3 = 0.f;
        #pragma unroll 8
        for (int c = 0; c < CIMG; ++c) {
            float w = w1[c * H1D + t];
            a0 += x_s[0][c] * w;
            a1 += x_s[1][c] * w;
            a2 += x_s[2][c] * w;
            a3 += x_s[3][c] * w;
        }
        float bias = b1[t];
        float scale = rsqrtf(v1[t] + EPSF) * g1[t];
        float off = bt1[t] - m1[t] * scale;
        h1_s[0][t] = fmaxf(0.f, (a0 + bias) * scale + off);
        h1_s[1][t] = fmaxf(0.f, (a1 + bias) * scale + off);
        h1_s[2][t] = fmaxf(0.f, (a2 + bias) * scale + off);
        h1_s[3][t] = fmaxf(0.f, (a3 + bias) * scale + off);
    }
    __syncthreads();

    // layer 2: o = t&127, rows (t>>7)*2, +1
    {
        int o = t & (H2D - 1);
        int r0 = (t >> 7) * 2;
        float a0 = 0.f, a1 = 0.f;
        #pragma unroll 8
        for (int c = 0; c < H1D; ++c) {
            float w = w2[c * H2D + o];
            a0 += h1_s[r0][c] * w;
            a1 += h1_s[r0 + 1][c] * w;
        }
        float bias = b2[o];
        float scale = rsqrtf(v2[o] + EPSF) * g2[o];
        float off = bt2[o] - m2[o] * scale;
        h2_s[r0][o] = fmaxf(0.f, (a0 + bias) * scale + off);
        h2_s[r0 + 1][o] = fmaxf(0.f, (a1 + bias) * scale + off);
    }
    __syncthreads();

    // layer 3: o = t&63, row = t>>6
    {
        int o = t & 63, r = t >> 6;
        float a = 0.f;
        #pragma unroll 8
        for (int c = 0; c < H2D; ++c) a += h2_s[r][c] * w3[c * H3D + o];
        h3_s[r][o] = fmaxf(0.f, a + b3[o]);
    }
    __syncthreads();

    // layer 4: 4 rows x 8 outs = 32 tasks
    if (t < 4 * UD) {
        int o = t & (UD - 1), r = t >> 3;
        float a = bnc[o];
        #pragma unroll
        for (int c = 0; c < H3D; ++c) a += h3_s[r][c] * wn[c * UD + o];
        node_c[(size_t)(row0 + r) * UD + o] = 1.f / (1.f + expf(-a));
    }
}

// ---------------------------------------------------------------------------
// Kernel 3: edge MLP — one thread per pair (b,i,j).
// e1 = relu(P[b,i]+Q[b,j]); e2 = relu(e1@we2+be2) streamed; rel = sigmoid(e2@wei+bei)
// Grid: BB*16 blocks x 256 threads (4 i's x 64 j per block).
// Q staged in LDS with +1 pad (row stride 65 -> conflict-free per-lane rows).
// we2/wei/be2/bei read with wave-uniform addresses (scalar-load path).
// ---------------------------------------------------------------------------
__global__ __launch_bounds__(256) void edge_mlp_kernel(
    const float* __restrict__ P, const float* __restrict__ Q,
    const float* __restrict__ we2, const float* __restrict__ be2,
    const float* __restrict__ wei, const float* __restrict__ bei,
    float* __restrict__ rel)
{
    __shared__ float Q_s[NN][EH1D + 1];

    const int t = threadIdx.x;
    const int b = blockIdx.x >> 4;
    const int i0 = (blockIdx.x & 15) * 4;

    for (int x = t; x < NN * EH1D; x += 256)
        Q_s[x >> 6][x & 63] = Q[(size_t)b * NN * EH1D + x];
    __syncthreads();

    const int il = t >> 6;       // wave-uniform
    const int j = t & 63;
    const int i = i0 + il;

    const float* Pi = P + (size_t)(b * NN + i) * EH1D;  // wave-uniform base

    float e1[EH1D];
    #pragma unroll
    for (int o = 0; o < EH1D; ++o)
        e1[o] = fmaxf(0.f, Pi[o] + Q_s[j][o]);

    float acc[RD];
    #pragma unroll
    for (int r = 0; r < RD; ++r) acc[r] = bei[r];

    for (int o2 = 0; o2 < EH2D; ++o2) {
        float a = be2[o2];
        #pragma unroll
        for (int c = 0; c < EH1D; ++c) a += e1[c] * we2[c * EH2D + o2];
        a = fmaxf(0.f, a);
        #pragma unroll
        for (int r = 0; r < RD; ++r) acc[r] += a * wei[o2 * RD + r];
    }

    float* out = rel + (size_t)(((b * NN + i) * NN) + j) * RD;
    float4 o0, o1;
    o0.x = 1.f / (1.f + expf(-acc[0]));
    o0.y = 1.f / (1.f + expf(-acc[1]));
    o0.z = 1.f / (1.f + expf(-acc[2]));
    o0.w = 1.f / (1.f + expf(-acc[3]));
    o1.x = 1.f / (1.f + expf(-acc[4]));
    o1.y = 1.f / (1.f + expf(-acc[5]));
    o1.z = 1.f / (1.f + expf(-acc[6]));
    o1.w = 1.f / (1.f + expf(-acc[7]));
    ((float4*)out)[0] = o0;
    ((float4*)out)[1] = o1;
}

// ---------------------------------------------------------------------------
// Kernel 4: node_concepts gather. out[b,i,k,:] = node_c[b, see[b,i,k], :] * m
// Grid: 256 blocks x 256 threads (one thread per (b,i,k)).
// ---------------------------------------------------------------------------
__global__ __launch_bounds__(256) void node_gather_kernel(
    const int* __restrict__ see, const int* __restrict__ cnt,
    const float* __restrict__ node_c, float* __restrict__ out)
{
    const int idx = blockIdx.x * 256 + threadIdx.x;   // (b*NN+i)*NN + k
    const int k = idx & 63;
    const int bi = idx >> 6;
    const int b = bi >> 6;
    const int s = see[idx];
    const float m = (k < cnt[bi]) ? 1.f : 0.f;

    const float4* src = (const float4*)(node_c + (size_t)(b * NN + s) * UD);
    float4 v0 = src[0], v1 = src[1];
    v0.x *= m; v0.y *= m; v0.z *= m; v0.w *= m;
    v1.x *= m; v1.y *= m; v1.z *= m; v1.w *= m;
    float4* dst = (float4*)(out + (size_t)idx * UD);
    dst[0] = v0;
    dst[1] = v1;
}

// ---------------------------------------------------------------------------
// Kernel 5: edge_concepts gather. out[b,i,j,k,:] = rel[b, s[j], s[k], :] *
// m[j]*m[k]  with s = see[b,i,:], m from count. Mask values are exactly 0/1,
// so masked entries are pure zero-writes (no rel read) — ~98% of lanes.
// Grid: BB*NN = 1024 blocks x 256 threads.
// ---------------------------------------------------------------------------
__global__ __launch_bounds__(256) void edge_gather_kernel(
    const int* __restrict__ see, const int* __restrict__ cnt,
    const float* __restrict__ rel, float* __restrict__ out)
{
    __shared__ int s_s[NN];
    __shared__ float m_s[NN];

    const int t = threadIdx.x;
    const int bi = blockIdx.x;        // b*NN + i
    const int b = bi >> 6;

    if (t < NN) {
        s_s[t] = see[bi * NN + t];
        m_s[t] = (t < cnt[bi]) ? 1.f : 0.f;
    }
    __syncthreads();

    const float* relb = rel + (size_t)b * NN * NN * RD;
    float* outb = out + (size_t)bi * NN * NN * RD;

    #pragma unroll
    for (int it = 0; it < (NN * NN) / 256; ++it) {
        int task = it * 256 + t;
        int j = task >> 6, k = task & 63;
        float m = m_s[j] * m_s[k];
        float4 v0 = make_float4(0.f, 0.f, 0.f, 0.f);
        float4 v1 = v0;
        if (m != 0.f) {
            const float4* src =
                (const float4*)(relb + (size_t)(s_s[j] * NN + s_s[k]) * RD);
            v0 = src[0];
            v1 = src[1];
        }
        float4* dst = (float4*)(outb + (size_t)task * RD);
        dst[0] = v0;
        dst[1] = v1;
    }
}

// ---------------------------------------------------------------------------
extern "C" void kernel_launch(void* const* d_in, const int* in_sizes, int n_in,
                              void* d_out, int out_size, void* d_ws, size_t ws_size,
                              hipStream_t stream)
{
    const float* roi  = (const float*)d_in[0];
    const float* bbox = (const float*)d_in[1];
    const float* dirs = (const float*)d_in[2];
    const float* prio = (const float*)d_in[3];
    const float* w1   = (const float*)d_in[4];
    const float* b1   = (const float*)d_in[5];
    const float* g1   = (const float*)d_in[6];
    const float* bt1  = (const float*)d_in[7];
    const float* m1   = (const float*)d_in[8];
    const float* v1   = (const float*)d_in[9];
    const float* w2   = (const float*)d_in[10];
    const float* b2   = (const float*)d_in[11];
    const float* g2   = (const float*)d_in[12];
    const float* bt2  = (const float*)d_in[13];
    const float* m2   = (const float*)d_in[14];
    const float* v2   = (const float*)d_in[15];
    const float* w3   = (const float*)d_in[16];
    const float* b3   = (const float*)d_in[17];
    const float* wn   = (const float*)d_in[18];
    const float* bnc  = (const float*)d_in[19];
    const float* we1  = (const float*)d_in[20];
    const float* be1  = (const float*)d_in[21];
    const float* we2  = (const float*)d_in[22];
    const float* be2  = (const float*)d_in[23];
    const float* wei  = (const float*)d_in[24];
    const float* bei  = (const float*)d_in[25];
    const int* edge_index = (const int*)d_in[26];

    char* ws = (char*)d_ws;
    int*   see    = (int*)ws;   ws += (size_t)BB * NN * NN * 4;   // 256 KB
    int*   cnt    = (int*)ws;   ws += (size_t)BB * NN * 4;        // 4 KB
    float* Pbuf   = (float*)ws; ws += (size_t)BB * NN * EH1D * 4; // 256 KB
    float* Qbuf   = (float*)ws; ws += (size_t)BB * NN * EH1D * 4; // 256 KB
    float* node_c = (float*)ws; ws += (size_t)BB * NN * UD * 4;   // 32 KB
    float* rel    = (float*)ws; ws += (size_t)BB * NN * NN * RD * 4; // 2 MB

    float* out_node = (float*)d_out;                       // B*N*N*U
    float* out_edge = (float*)d_out + (size_t)BB * NN * NN * UD;

    hipLaunchKernelGGL(prep_kernel, dim3(BB), dim3(256), 0, stream,
                       edge_index, bbox, dirs, prio, we1, be1,
                       see, cnt, Pbuf, Qbuf);
    hipLaunchKernelGGL(node_mlp_kernel, dim3(256), dim3(256), 0, stream,
                       roi, w1, b1, g1, bt1, m1, v1,
                       w2, b2, g2, bt2, m2, v2,
                       w3, b3, wn, bnc, node_c);
    hipLaunchKernelGGL(edge_mlp_kernel, dim3(BB * 16), dim3(256), 0, stream,
                       Pbuf, Qbuf, we2, be2, wei, bei, rel);
    hipLaunchKernelGGL(node_gather_kernel, dim3(256), dim3(256), 0, stream,
                       see, cnt, node_c, out_node);
    hipLaunchKernelGGL(edge_gather_kernel, dim3(BB * NN), dim3(256), 0, stream,
                       see, cnt, rel, out_edge);
}